// Round 1
// baseline (175.086 us; speedup 1.0000x reference)
//
#include <hip/hip_runtime.h>

#define C_IN 256
#define CR   64      // C / reduction
#define G_   16      // groups
#define GC_  16      // group channels
#define K_   7
#define KK   49
#define PAD_ 3
#define H_   64
#define W_   64
#define HW   4096
#define OO   784     // K*K*G
#define EPSV 1e-5f

// ---------------- transpose: dst[c][r] = src[r][c] ----------------
__global__ __launch_bounds__(256) void transpose_kernel(
    const float* __restrict__ src, float* __restrict__ dst, int rows, int cols)
{
  int idx = blockIdx.x * 256 + threadIdx.x;
  if (idx < rows * cols) {
    int r = idx / cols, c = idx % cols;
    dst[c * rows + r] = src[idx];
  }
}

// ---------------- conv1 (1x1, 256->64) + BN + ReLU ----------------
// block: 256 thr = 64 px * 4 j ; each thread computes 16 channels o = j*16+jo
// grid: (HW/64, B)
__global__ __launch_bounds__(256) void conv1_kernel(
    const float* __restrict__ x, const float* __restrict__ w1t,  // w1t[c][o], 256x64
    const float* __restrict__ b1, const float* __restrict__ gamma,
    const float* __restrict__ beta, const float* __restrict__ mean,
    const float* __restrict__ var, float* __restrict__ t)
{
  __shared__ float xs[C_IN][64];                    // 64 KB
  const int px  = threadIdx.x & 63;
  const int ju  = __builtin_amdgcn_readfirstlane(threadIdx.x >> 6);  // wave-uniform
  const int hw0 = blockIdx.x * 64;
  const int b   = blockIdx.y;
  const float* xb = x + ((size_t)b * C_IN) * HW + hw0;

  for (int i = threadIdx.x; i < C_IN * 64; i += 256) {
    int c = i >> 6, p = i & 63;
    xs[c][p] = xb[(size_t)c * HW + p];
  }
  __syncthreads();

  float acc[16];
#pragma unroll
  for (int jo = 0; jo < 16; ++jo) acc[jo] = 0.f;

  for (int c = 0; c < C_IN; ++c) {
    float xv = xs[c][px];
    const float* wrow = w1t + c * CR + ju * 16;     // contiguous 16 floats, uniform
#pragma unroll
    for (int jo = 0; jo < 16; ++jo)
      acc[jo] = fmaf(xv, wrow[jo], acc[jo]);
  }

#pragma unroll
  for (int jo = 0; jo < 16; ++jo) {
    int o = ju * 16 + jo;
    float s = gamma[o] * rsqrtf(var[o] + EPSV);
    float v = s * (acc[jo] + b1[o] - mean[o]) + beta[o];
    v = fmaxf(v, 0.f);
    t[((size_t)b * CR + o) * HW + hw0 + px] = v;
  }
}

// ---------------- conv2 (1x1, 64->784): weight map ----------------
// block: 256 thr = 64 px * 4 j ; thread computes 16 contiguous oo starting at
// oo0 = (blockIdx.y*4 + j)*16.  grid: (HW/64, 13, nb)  (52 groups cover 49)
__global__ __launch_bounds__(256) void conv2_kernel(
    const float* __restrict__ t, const float* __restrict__ w2t,  // w2t[c][oo], 64x784
    const float* __restrict__ b2, float* __restrict__ wbuf)
{
  __shared__ float ts[CR][64];                      // 16 KB
  const int px  = threadIdx.x & 63;
  const int ju  = __builtin_amdgcn_readfirstlane(threadIdx.x >> 6);
  const int hw0 = blockIdx.x * 64;
  const int b   = blockIdx.z;
  const float* tb = t + ((size_t)b * CR) * HW + hw0;

  for (int i = threadIdx.x; i < CR * 64; i += 256) {
    int c = i >> 6, p = i & 63;
    ts[c][p] = tb[(size_t)c * HW + p];
  }
  __syncthreads();

  const int oo0 = (blockIdx.y * 4 + ju) * 16;
  if (oo0 >= OO) return;                            // no further barriers below

  float acc[16];
#pragma unroll
  for (int q = 0; q < 16; ++q) acc[q] = 0.f;

  for (int c = 0; c < CR; ++c) {
    float xv = ts[c][px];
    const float* wrow = w2t + c * OO + oo0;         // contiguous 16 floats, uniform
#pragma unroll
    for (int q = 0; q < 16; ++q)
      acc[q] = fmaf(xv, wrow[q], acc[q]);
  }

#pragma unroll
  for (int q = 0; q < 16; ++q)
    wbuf[((size_t)b * OO + oo0 + q) * HW + hw0 + px] = acc[q] + b2[oo0 + q];
}

// ---------------- involution apply ----------------
// thread = one pixel; 49 weights in registers, reused for 16 group channels.
// grid: (HW/256, G, nb)
__global__ __launch_bounds__(256) void invol_kernel(
    const float* __restrict__ x, const float* __restrict__ wbuf,
    float* __restrict__ out)
{
  const int hw = blockIdx.x * 256 + threadIdx.x;
  const int g  = blockIdx.y;
  const int b  = blockIdx.z;
  const int h  = hw >> 6, w = hw & 63;

  float wreg[KK];
#pragma unroll
  for (int kk = 0; kk < KK; ++kk)
    wreg[kk] = wbuf[((size_t)b * OO + g * KK + kk) * HW + hw];

  const float* xb = x   + ((size_t)b * C_IN + g * GC_) * HW;
  float*       ob = out + ((size_t)b * C_IN + g * GC_) * HW;

#pragma unroll 1
  for (int gc = 0; gc < GC_; ++gc) {
    float acc = 0.f;
#pragma unroll
    for (int kk = 0; kk < KK; ++kk) {
      const int dh = kk / K_ - PAD_, dw = kk % K_ - PAD_;
      int y = h + dh, xx = w + dw;
      float xv = (y >= 0 && y < H_ && xx >= 0 && xx < W_)
                   ? xb[(size_t)gc * HW + y * W_ + xx] : 0.f;
      acc = fmaf(wreg[kk], xv, acc);
    }
    ob[(size_t)gc * HW + hw] = acc;
  }
}

extern "C" void kernel_launch(void* const* d_in, const int* in_sizes, int n_in,
                              void* d_out, int out_size, void* d_ws, size_t ws_size,
                              hipStream_t stream) {
  const float* x     = (const float*)d_in[0];
  const float* w1    = (const float*)d_in[1];
  const float* b1    = (const float*)d_in[2];
  const float* gamma = (const float*)d_in[3];
  const float* beta  = (const float*)d_in[4];
  const float* mean  = (const float*)d_in[5];
  const float* var   = (const float*)d_in[6];
  const float* w2    = (const float*)d_in[7];
  const float* b2    = (const float*)d_in[8];
  float* out = (float*)d_out;
  const int B = in_sizes[0] / (C_IN * HW);

  // ws layout: [w1t 64KB][w2t 200KB+pad][t B*1MB][wbuf ...]
  char* p = (char*)d_ws;
  float* w1t = (float*)p;                 p += ((size_t)CR * C_IN * 4 + 255) & ~(size_t)255;
  float* w2t = (float*)p;                 p += ((size_t)OO * CR  * 4 + 255) & ~(size_t)255;
  float* t   = (float*)p;                 p += ((size_t)B * CR * HW * 4 + 255) & ~(size_t)255;
  float* wbuf = (float*)p;
  size_t used   = (size_t)(p - (char*)d_ws);
  size_t wbFull = (size_t)B * OO * HW * 4;
  bool full = (ws_size >= used + wbFull);

  transpose_kernel<<<dim3((CR * C_IN + 255) / 256), 256, 0, stream>>>(w1, w1t, CR, C_IN);
  transpose_kernel<<<dim3((OO * CR  + 255) / 256), 256, 0, stream>>>(w2, w2t, OO, CR);

  conv1_kernel<<<dim3(HW / 64, B), 256, 0, stream>>>(x, w1t, b1, gamma, beta, mean, var, t);

  if (full) {
    conv2_kernel<<<dim3(HW / 64, 13, B), 256, 0, stream>>>(t, w2t, b2, wbuf);
    invol_kernel<<<dim3(HW / 256, G_, B), 256, 0, stream>>>(x, wbuf, out);
  } else {
    // reuse one per-batch weight buffer; stream order serializes correctly
    for (int b = 0; b < B; ++b) {
      conv2_kernel<<<dim3(HW / 64, 13, 1), 256, 0, stream>>>(
          t + (size_t)b * CR * HW, w2t, b2, wbuf);
      invol_kernel<<<dim3(HW / 256, G_, 1), 256, 0, stream>>>(
          x + (size_t)b * C_IN * HW, wbuf, out + (size_t)b * C_IN * HW);
    }
  }
}